// Round 5
// baseline (423.603 us; speedup 1.0000x reference)
//
#include <hip/hip_runtime.h>

// 4-layer GRU stack, B=4096, T=256. 256 persistent blocks x 768 threads
// (12 waves, 3 per SIMD), 16 batch rows per block (one M=16 MFMA tile).
//
// R5 change: activations are TRANS-FREE. Measured across R1-R4,
// v_exp_f32/v_rcp_f32 cost ~32 cyc/wave64 and serialize per SIMD; the 60
// trans-instrs/SIMD/step (1920 cyc) were ~80% of the step. Replaced with:
//   exp2: magic-round + deg-5 Taylor + exponent bit-add  (full-rate FMA/int)
//   rcp : magic-constant estimate + 2 Newton iterations  (full-rate FMA)
// Everything else (balanced 12-wave layer pipeline, 1 barrier/step, chunked
// x staging, padded LDS strides) unchanged from R4.

typedef __attribute__((ext_vector_type(8))) __bf16 bf16x8;
typedef __attribute__((ext_vector_type(4))) float f32x4;

#define TT 256
#define FF 20
#define BT 16
#define CH 64      // x chunk steps held in LDS
#define SH0 72     // h0 LDS row stride (bf16), padded from 64
#define SH1 40     // h1/h2/h3 LDS row stride, padded from 32
#define XSTR 648   // x_ch t-plane stride (bf16): 16*40 + 8 pad
#define NTHR 768
#define LOG2E 1.44269504f

__device__ __forceinline__ f32x4 mfma16(bf16x8 a, bf16x8 b, f32x4 c) {
  return __builtin_amdgcn_mfma_f32_16x16x32_bf16(a, b, c, 0, 0, 0);
}

// 2^y for y in [-44, 44] (caller clamps). FMA/int pipe only, no trans.
// Magic-add rounds y to nearest int n (RNE); bits(nf)<<23 == n<<23 exactly
// (low 9 bits of bits(1.5*2^23) are zero, |n| < 256). Deg-5 Taylor of 2^f
// on [-0.5,0.5]: rel err ~2.4e-6.
__device__ __forceinline__ float exp2s(float y) {
  const float MAGIC = 12582912.f;  // 1.5 * 2^23
  float nf = y + MAGIC;
  int   sc = __float_as_int(nf) << 23;
  float n  = nf - MAGIC;
  float f  = y - n;
  float p  = fmaf(f, 0.0013333558f, 0.0096181291f);
  p = fmaf(f, p, 0.0555041087f);
  p = fmaf(f, p, 0.2402265070f);
  p = fmaf(f, p, 0.6931471806f);
  p = fmaf(f, p, 1.0f);
  return __int_as_float(__float_as_int(p) + sc);
}

// fast 1/x for x in [1, 2^90): magic estimate (<~10% err) + 2 Newton
// iterations -> ~1e-4 rel err. FMA pipe only, no trans.
__device__ __forceinline__ float rcps(float x) {
  float r = __int_as_float(0x7EF127EBu - (unsigned)__float_as_int(x));
  r = r * fmaf(-x, r, 2.f);
  r = r * fmaf(-x, r, 2.f);
  return r;
}

// B-operand fragment from global row-major W[K][N]: lane holds col n, k=kbase+j.
__device__ __forceinline__ bf16x8 bfragW(const float* W, int Kreal, int N,
                                         int ncol, int kbase) {
  bf16x8 r;
#pragma unroll
  for (int j = 0; j < 8; ++j) {
    int k = kbase + j;
    r[j] = (__bf16)(k < Kreal ? W[k * N + ncol] : 0.f);
  }
  return r;
}

extern "C" __global__ void __launch_bounds__(NTHR, 3)
gru4(const float* __restrict__ inp, const float* __restrict__ Wemb,
     const float* __restrict__ k0, const float* __restrict__ rk0, const float* __restrict__ b0,
     const float* __restrict__ k1, const float* __restrict__ rk1, const float* __restrict__ b1,
     const float* __restrict__ k2, const float* __restrict__ rk2, const float* __restrict__ b2,
     const float* __restrict__ k3, const float* __restrict__ rk3, const float* __restrict__ b3,
     const float* __restrict__ Wd, const float* __restrict__ bd,
     float* __restrict__ out)
{
  __shared__ __align__(16) __bf16 x_ch[CH * XSTR];       // ~83 KB
  __shared__ __align__(16) __bf16 h0_lds[2][BT * SH0];
  __shared__ __align__(16) __bf16 h1_lds[2][BT * SH1];
  __shared__ __align__(16) __bf16 h2_lds[2][BT * SH1];
  __shared__ __align__(16) __bf16 h3_lds[2][BT * SH1];
  __shared__ __align__(16) float h3f[BT * 32];

  const int tid  = threadIdx.x;
  const int lane = tid & 63;
  const int w    = tid >> 6;        // wave 0..11
  const int col  = lane & 15;       // C col / B n / A m index
  const int kb   = (lane >> 4) * 8; // A/B k base within a k-tile
  const int rowq = (lane >> 4) * 4; // C row base (batch)
  const long bbase = (long)blockIdx.x * BT;
  const float* binp = inp + bbase * TT * FF;

  bf16x8 zf;
#pragma unroll
  for (int j = 0; j < 8; ++j) zf[j] = (__bf16)0.f;

  // ---- uniform per-wave job config (shared variables across all roles) ----
  bf16x8 Wz0 = zf, Wz1 = zf, Wz2 = zf;
  bf16x8 Wr0 = zf, Wr1 = zf, Wr2 = zf;
  bf16x8 Wgx0 = zf, Wgx1 = zf, Wgx2 = zf;
  bf16x8 Wgh0 = zf, Wgh1 = zf, Wgh2 = zf;
  float bz = 0.f, br = 0.f, bxh = 0.f, bhh = 0.f;
  const __bf16 *A0b = x_ch, *A1b = x_ch, *A2b = x_ch;
  int D0 = 0, D1 = 0, D2 = 0;
  __bf16* Wwr0 = (__bf16*)h3f;
  int WD = 0, wstride = SH1;
  int lay = 0;
  bool doLo = false, doHi = false, threeA = false;

  if (w < 6) {
    // L0: w0..w3 = row-halves of slices 0,1; w4,w5 = full slices 2,3.
    lay = 0; threeA = true;
    const int sl = (w < 4) ? (w >> 1) : (w - 2);
    doLo = (w >= 4) || ((w & 1) == 0);
    doHi = (w >= 4) || ((w & 1) == 1);
    const int u = sl * 16 + col;
    Wz0 = bfragW(k0, 23, 192, u, kb);
    Wz1 = bfragW(rk0, 64, 192, u, kb);
    Wz2 = bfragW(rk0, 64, 192, u, 32 + kb);
    Wr0 = bfragW(k0, 23, 192, 64 + u, kb);
    Wr1 = bfragW(rk0, 64, 192, 64 + u, kb);
    Wr2 = bfragW(rk0, 64, 192, 64 + u, 32 + kb);
    Wgx0 = bfragW(k0, 23, 192, 128 + u, kb);
    Wgh1 = bfragW(rk0, 64, 192, 128 + u, kb);
    Wgh2 = bfragW(rk0, 64, 192, 128 + u, 32 + kb);
    bz  = b0[u] + b0[192 + u];
    br  = b0[64 + u] + b0[192 + 64 + u];
    bxh = b0[128 + u];
    bhh = b0[192 + 128 + u];
    A1b = &h0_lds[0][col * SH0 + kb];      D1 = BT * SH0;
    A2b = &h0_lds[0][col * SH0 + 32 + kb]; D2 = BT * SH0;
    Wwr0 = &h0_lds[0][rowq * SH0 + sl * 16 + col];
    WD = BT * SH0; wstride = SH0;
  } else if (w < 8) {
    // L1: slices 0,1 full.
    lay = 1; threeA = true; doLo = doHi = true;
    const int u = (w - 6) * 16 + col;
    Wz0 = bfragW(k1, 64, 96, u, kb);
    Wz1 = bfragW(k1, 64, 96, u, 32 + kb);
    Wz2 = bfragW(rk1, 32, 96, u, kb);
    Wr0 = bfragW(k1, 64, 96, 32 + u, kb);
    Wr1 = bfragW(k1, 64, 96, 32 + u, 32 + kb);
    Wr2 = bfragW(rk1, 32, 96, 32 + u, kb);
    Wgx0 = bfragW(k1, 64, 96, 64 + u, kb);
    Wgx1 = bfragW(k1, 64, 96, 64 + u, 32 + kb);
    Wgh2 = bfragW(rk1, 32, 96, 64 + u, kb);
    bz  = b1[u] + b1[96 + u];
    br  = b1[32 + u] + b1[96 + 32 + u];
    bxh = b1[64 + u];
    bhh = b1[96 + 64 + u];
    A0b = &h0_lds[0][col * SH0 + kb];      D0 = BT * SH0;
    A1b = &h0_lds[0][col * SH0 + 32 + kb]; D1 = BT * SH0;
    A2b = &h1_lds[0][col * SH1 + kb];      D2 = BT * SH1;
    Wwr0 = &h1_lds[0][rowq * SH1 + (w - 6) * 16 + col];
    WD = BT * SH1; wstride = SH1;
  } else if (w < 10) {
    // L2: slices 0,1 full.
    lay = 2; threeA = false; doLo = doHi = true;
    const int u = (w - 8) * 16 + col;
    Wz0 = bfragW(k2, 32, 96, u, kb);
    Wz1 = bfragW(rk2, 32, 96, u, kb);
    Wr0 = bfragW(k2, 32, 96, 32 + u, kb);
    Wr1 = bfragW(rk2, 32, 96, 32 + u, kb);
    Wgx0 = bfragW(k2, 32, 96, 64 + u, kb);
    Wgh1 = bfragW(rk2, 32, 96, 64 + u, kb);
    bz  = b2[u] + b2[96 + u];
    br  = b2[32 + u] + b2[96 + 32 + u];
    bxh = b2[64 + u];
    bhh = b2[96 + 64 + u];
    A0b = &h1_lds[0][col * SH1 + kb]; D0 = BT * SH1;
    A1b = &h2_lds[0][col * SH1 + kb]; D1 = BT * SH1;
    A2b = A1b; D2 = D1;
    Wwr0 = &h2_lds[0][rowq * SH1 + (w - 8) * 16 + col];
    WD = BT * SH1; wstride = SH1;
  } else {
    // L3: slices 0,1 full.
    lay = 3; threeA = false; doLo = doHi = true;
    const int u = (w - 10) * 16 + col;
    Wz0 = bfragW(k3, 32, 96, u, kb);
    Wz1 = bfragW(rk3, 32, 96, u, kb);
    Wr0 = bfragW(k3, 32, 96, 32 + u, kb);
    Wr1 = bfragW(rk3, 32, 96, 32 + u, kb);
    Wgx0 = bfragW(k3, 32, 96, 64 + u, kb);
    Wgh1 = bfragW(rk3, 32, 96, 64 + u, kb);
    bz  = b3[u] + b3[96 + u];
    br  = b3[32 + u] + b3[96 + 32 + u];
    bxh = b3[64 + u];
    bhh = b3[96 + 64 + u];
    A0b = &h2_lds[0][col * SH1 + kb]; D0 = BT * SH1;
    A1b = &h3_lds[0][col * SH1 + kb]; D1 = BT * SH1;
    A2b = A1b; D2 = D1;
    Wwr0 = &h3_lds[0][rowq * SH1 + (w - 10) * 16 + col];
    WD = BT * SH1; wstride = SH1;
  }

  const __bf16* xb = &x_ch[col * 40 + kb];  // L0 x A-frag base (per t-plane)

  // ------------- zero-init h state -------------
  {
    __bf16* p0 = (__bf16*)h0_lds;
    for (int i = tid; i < 2 * BT * SH0; i += NTHR) p0[i] = (__bf16)0.f;
    __bf16* p1 = (__bf16*)h1_lds;
    __bf16* p2 = (__bf16*)h2_lds;
    __bf16* p3 = (__bf16*)h3_lds;
    for (int i = tid; i < 2 * BT * SH1; i += NTHR) {
      p1[i] = (__bf16)0.f; p2[i] = (__bf16)0.f; p3[i] = (__bf16)0.f;
    }
  }
  float hreg[4] = {0.f, 0.f, 0.f, 0.f};
  __syncthreads();

  for (int s = 0; s < TT + 3; ++s) {
    // ---- bulk x staging every CH steps ----
    if ((s & (CH - 1)) == 0 && s < TT) {
      for (int idx = tid; idx < BT * CH; idx += NTHR) {
        const int row = idx >> 6;          // CH = 64
        const int tg  = idx & (CH - 1);
        const float* p = binp + ((long)row * TT + s + tg) * FF;
        float4 v0 = *(const float4*)(p);
        float4 v1 = *(const float4*)(p + 4);
        float4 v2 = *(const float4*)(p + 8);
        float4 v3 = *(const float4*)(p + 12);
        float4 v4 = *(const float4*)(p + 16);
        float4 e  = *(const float4*)(Wemb + 4 * (int)v0.y);
        __bf16* d = &x_ch[tg * XSTR + row * 40];
        bf16x8 q0 = {(__bf16)v0.x, (__bf16)v0.z, (__bf16)v0.w, (__bf16)v1.x,
                     (__bf16)v1.y, (__bf16)v1.z, (__bf16)v1.w, (__bf16)v2.x};
        bf16x8 q1 = {(__bf16)v2.y, (__bf16)v2.z, (__bf16)v2.w, (__bf16)v3.x,
                     (__bf16)v3.y, (__bf16)v3.z, (__bf16)v3.w, (__bf16)v4.x};
        bf16x8 q2 = {(__bf16)v4.y, (__bf16)v4.z, (__bf16)v4.w, (__bf16)e.x,
                     (__bf16)e.y,  (__bf16)e.z,  (__bf16)e.w,  (__bf16)0.f};
        *(bf16x8*)(d)      = q0;
        *(bf16x8*)(d + 8)  = q1;
        *(bf16x8*)(d + 16) = q2;
        *(bf16x8*)(d + 24) = zf;
      }
      __syncthreads();
    }

    const int pb = (s + 1) & 1;  // read buffer (previous step's writes)
    const int qb = s & 1;        // write buffer
    const int t  = s - lay;

    if (t >= 0 && t < TT) {
      const __bf16* a0p = (lay == 0) ? (xb + (s & (CH - 1)) * XSTR)
                                     : (A0b + pb * D0);
      bf16x8 A0 = *(const bf16x8*)a0p;
      bf16x8 A1 = *(const bf16x8*)(A1b + pb * D1);
      f32x4 az  = {bz, bz, bz, bz};
      f32x4 ar  = {br, br, br, br};
      f32x4 axh = {bxh, bxh, bxh, bxh};
      f32x4 ahh = {bhh, bhh, bhh, bhh};
      az  = mfma16(A0, Wz0, az);   az  = mfma16(A1, Wz1, az);
      ar  = mfma16(A0, Wr0, ar);   ar  = mfma16(A1, Wr1, ar);
      axh = mfma16(A0, Wgx0, axh); axh = mfma16(A1, Wgx1, axh);
      ahh = mfma16(A0, Wgh0, ahh); ahh = mfma16(A1, Wgh1, ahh);
      if (threeA) {
        bf16x8 A2 = *(const bf16x8*)(A2b + pb * D2);
        az  = mfma16(A2, Wz2, az);
        ar  = mfma16(A2, Wr2, ar);
        axh = mfma16(A2, Wgx2, axh);
        ahh = mfma16(A2, Wgh2, ahh);
      }
      __bf16* wr = Wwr0 + qb * WD;

      // Trans-free gates: sigm(x)=1/(1+2^(-x*log2e)), tanh(u)=2/(1+2^(-2u*log2e))-1
      // One shared Newton-rcp for the z/r denominators, one for tanh.
#define GATE(r) { \
        float yz = fminf(fmaxf(az[r] * -LOG2E, -36.f), 36.f); \
        float yr = fminf(fmaxf(ar[r] * -LOG2E, -36.f), 36.f); \
        float Ez = exp2s(yz); \
        float Er = exp2s(yr); \
        float dz = 1.f + Ez; \
        float dr = 1.f + Er; \
        float inv = rcps(dz * dr); \
        float z  = inv * dr; \
        float rg = inv * dz; \
        float u  = fminf(fmaxf(fmaf(rg, ahh[r], axh[r]), -15.f), 15.f); \
        float Eg = exp2s(u * (-2.f * LOG2E)); \
        float ivg = rcps(1.f + Eg); \
        float hc = fmaf(2.f, ivg, -1.f); \
        float hn = fmaf(z, hreg[r] - hc, hc); \
        hreg[r] = hn; \
        wr[(r) * wstride] = (__bf16)hn; }

      if (doLo) { GATE(0); GATE(1); }
      if (doHi) { GATE(2); GATE(3); }
#undef GATE
    }

    __syncthreads();   // single per-step barrier
  }

  // ------------- epilogue: logits + softmax -------------
  if (w >= 10) {
#pragma unroll
    for (int r = 0; r < 4; ++r)
      h3f[(rowq + r) * 32 + (w - 10) * 16 + col] = hreg[r];
  }
  __syncthreads();

  if (tid < BT) {
    float l0 = bd[0], l1 = bd[1];
#pragma unroll
    for (int u = 0; u < 32; ++u) {
      float h = h3f[tid * 32 + u];
      l0 = fmaf(h, Wd[2 * u], l0);
      l1 = fmaf(h, Wd[2 * u + 1], l1);
    }
    float m = fmaxf(l0, l1);
    float e0 = __builtin_amdgcn_exp2f((l0 - m) * LOG2E);
    float e1 = __builtin_amdgcn_exp2f((l1 - m) * LOG2E);
    float inv = 1.f / (e0 + e1);
    out[(bbase + tid) * 2 + 0] = e0 * inv;
    out[(bbase + tid) * 2 + 1] = e1 * inv;
  }
}

extern "C" void kernel_launch(void* const* d_in, const int* in_sizes, int n_in,
                              void* d_out, int out_size, void* d_ws, size_t ws_size,
                              hipStream_t stream) {
  const float* inp  = (const float*)d_in[0];
  const float* Wemb = (const float*)d_in[1];
  const float* k0   = (const float*)d_in[2];
  const float* rk0  = (const float*)d_in[3];
  const float* b0   = (const float*)d_in[4];
  const float* k1   = (const float*)d_in[5];
  const float* rk1  = (const float*)d_in[6];
  const float* b1   = (const float*)d_in[7];
  const float* k2   = (const float*)d_in[8];
  const float* rk2  = (const float*)d_in[9];
  const float* b2   = (const float*)d_in[10];
  const float* k3   = (const float*)d_in[11];
  const float* rk3  = (const float*)d_in[12];
  const float* b3   = (const float*)d_in[13];
  const float* Wd   = (const float*)d_in[14];
  const float* bd   = (const float*)d_in[15];
  float* out = (float*)d_out;

  const int Btot = in_sizes[0] / (TT * FF);   // 4096
  dim3 grid(Btot / BT);                       // 256 blocks
  gru4<<<grid, NTHR, 0, stream>>>(inp, Wemb, k0, rk0, b0, k1, rk1, b1,
                                  k2, rk2, b2, k3, rk3, b3, Wd, bd, out);
}

// Round 6
// 367.822 us; speedup vs baseline: 1.1517x; 1.1517x over previous
//
#include <hip/hip_runtime.h>

// 4-layer GRU stack, B=4096, T=256. 256 persistent blocks x 768 threads
// (12 waves, 3/SIMD), 16 batch rows per block (one M=16 MFMA tile).
//
// R6: deep pipeline skew t = s - 2*layer. Every cross-layer input is
// published TWO barriers before use -> prefetched into registers during the
// previous step (all step-s reads hit buf[(s-1)&1]; writes go buf[s&1] ->
// race-free with double buffering). Only the same-layer recurrent frag is
// read post-barrier, issued first and covered by MFMAs on prefetched regs.
// Exact MFMA sets per operand (no zero-weight padding MFMAs), and gates use
// one merged rcp for the z/r sigmoid pair (5 trans/row instead of 6).
// Measured model: trans ops cost ~16 issue-cyc each; R4's 40% idle was the
// post-barrier ds_read+MFMA serial phase this prefetch removes.

typedef __attribute__((ext_vector_type(8))) __bf16 bf16x8;
typedef __attribute__((ext_vector_type(4))) float f32x4;

#define TT 256
#define FF 20
#define BT 16
#define CH 64      // x chunk steps held in LDS
#define SH0 72     // h0 LDS row stride (bf16), padded from 64
#define SH1 40     // h1/h2/h3 LDS row stride, padded from 32
#define XSTR 648   // x_ch t-plane stride (bf16): 16*40 + 8 pad
#define NTHR 768
#define LOG2E 1.44269504f

__device__ __forceinline__ f32x4 mfma16(bf16x8 a, bf16x8 b, f32x4 c) {
  return __builtin_amdgcn_mfma_f32_16x16x32_bf16(a, b, c, 0, 0, 0);
}

// B-operand fragment from global row-major W[K][N]: lane holds col n, k=kbase+j.
__device__ __forceinline__ bf16x8 bfragW(const float* W, int Kreal, int N,
                                         int ncol, int kbase) {
  bf16x8 r;
#pragma unroll
  for (int j = 0; j < 8; ++j) {
    int k = kbase + j;
    r[j] = (__bf16)(k < Kreal ? W[k * N + ncol] : 0.f);
  }
  return r;
}

extern "C" __global__ void __launch_bounds__(NTHR, 3)
gru4(const float* __restrict__ inp, const float* __restrict__ Wemb,
     const float* __restrict__ k0, const float* __restrict__ rk0, const float* __restrict__ b0,
     const float* __restrict__ k1, const float* __restrict__ rk1, const float* __restrict__ b1,
     const float* __restrict__ k2, const float* __restrict__ rk2, const float* __restrict__ b2,
     const float* __restrict__ k3, const float* __restrict__ rk3, const float* __restrict__ b3,
     const float* __restrict__ Wd, const float* __restrict__ bd,
     float* __restrict__ out)
{
  __shared__ __align__(16) __bf16 x_ch[CH * XSTR];       // ~83 KB
  __shared__ __align__(16) __bf16 h0_lds[2][BT * SH0];
  __shared__ __align__(16) __bf16 h1_lds[2][BT * SH1];
  __shared__ __align__(16) __bf16 h2_lds[2][BT * SH1];
  __shared__ __align__(16) __bf16 h3_lds[2][BT * SH1];
  __shared__ __align__(16) float h3f[BT * 32];

  const int tid  = threadIdx.x;
  const int lane = tid & 63;
  const int w    = tid >> 6;        // wave 0..11
  const int col  = lane & 15;
  const int kb   = (lane >> 4) * 8;
  const int rowq = (lane >> 4) * 4;
  const long bbase = (long)blockIdx.x * BT;
  const float* binp = inp + bbase * TT * FF;

  bf16x8 zf;
#pragma unroll
  for (int j = 0; j < 8; ++j) zf[j] = (__bf16)0.f;

  // Operand roles: P0 = prefetched cross input (x / h_{l-1} kt0).
  //                X1 = second frag: L0 -> own h0 kt1 (post-barrier);
  //                                  L1 -> prefetched h0 kt1.
  //                O0 = own recurrent frag (post-barrier).
  bf16x8 WzP = zf, WrP = zf, WgP = zf;   // P0's g always -> axh
  bf16x8 WzX = zf, WrX = zf, WgX = zf;   // X1's g -> ahh (L0) or axh (L1)
  bf16x8 WzO = zf, WrO = zf, WgO = zf;   // O0's g always -> ahh
  float bz = 0.f, br = 0.f, bxh = 0.f, bhh = 0.f;
  const __bf16 *P0b = x_ch, *X1b = x_ch, *O0b = x_ch;
  int DP = 0, DX = 0, DO = 0;
  __bf16* Wwr0 = (__bf16*)h3f;
  int WD = 0, wstride = SH1;
  int lay = 0;
  bool doLo = false, doHi = false, hasX1pre = false, hasX1own = false;

  if (w < 6) {
    // L0: w0..w3 = row-halves of slices 0,1; w4,w5 = full slices 2,3.
    lay = 0; hasX1own = true;
    const int sl = (w < 4) ? (w >> 1) : (w - 2);
    doLo = (w >= 4) || ((w & 1) == 0);
    doHi = (w >= 4) || ((w & 1) == 1);
    const int u = sl * 16 + col;
    WzP = bfragW(k0, 23, 192, u, kb);
    WrP = bfragW(k0, 23, 192, 64 + u, kb);
    WgP = bfragW(k0, 23, 192, 128 + u, kb);
    WzO = bfragW(rk0, 64, 192, u, kb);
    WrO = bfragW(rk0, 64, 192, 64 + u, kb);
    WgO = bfragW(rk0, 64, 192, 128 + u, kb);
    WzX = bfragW(rk0, 64, 192, u, 32 + kb);
    WrX = bfragW(rk0, 64, 192, 64 + u, 32 + kb);
    WgX = bfragW(rk0, 64, 192, 128 + u, 32 + kb);
    bz  = b0[u] + b0[192 + u];
    br  = b0[64 + u] + b0[192 + 64 + u];
    bxh = b0[128 + u];
    bhh = b0[192 + 128 + u];
    O0b = &h0_lds[0][col * SH0 + kb];      DO = BT * SH0;
    X1b = &h0_lds[0][col * SH0 + 32 + kb]; DX = BT * SH0;
    Wwr0 = &h0_lds[0][rowq * SH0 + sl * 16 + col];
    WD = BT * SH0; wstride = SH0;
  } else if (w < 8) {
    lay = 1; hasX1pre = true; doLo = doHi = true;
    const int u = (w - 6) * 16 + col;
    WzP = bfragW(k1, 64, 96, u, kb);
    WrP = bfragW(k1, 64, 96, 32 + u, kb);
    WgP = bfragW(k1, 64, 96, 64 + u, kb);
    WzX = bfragW(k1, 64, 96, u, 32 + kb);
    WrX = bfragW(k1, 64, 96, 32 + u, 32 + kb);
    WgX = bfragW(k1, 64, 96, 64 + u, 32 + kb);
    WzO = bfragW(rk1, 32, 96, u, kb);
    WrO = bfragW(rk1, 32, 96, 32 + u, kb);
    WgO = bfragW(rk1, 32, 96, 64 + u, kb);
    bz  = b1[u] + b1[96 + u];
    br  = b1[32 + u] + b1[96 + 32 + u];
    bxh = b1[64 + u];
    bhh = b1[96 + 64 + u];
    P0b = &h0_lds[0][col * SH0 + kb];      DP = BT * SH0;
    X1b = &h0_lds[0][col * SH0 + 32 + kb]; DX = BT * SH0;
    O0b = &h1_lds[0][col * SH1 + kb];      DO = BT * SH1;
    Wwr0 = &h1_lds[0][rowq * SH1 + (w - 6) * 16 + col];
    WD = BT * SH1; wstride = SH1;
  } else if (w < 10) {
    lay = 2; doLo = doHi = true;
    const int u = (w - 8) * 16 + col;
    WzP = bfragW(k2, 32, 96, u, kb);
    WrP = bfragW(k2, 32, 96, 32 + u, kb);
    WgP = bfragW(k2, 32, 96, 64 + u, kb);
    WzO = bfragW(rk2, 32, 96, u, kb);
    WrO = bfragW(rk2, 32, 96, 32 + u, kb);
    WgO = bfragW(rk2, 32, 96, 64 + u, kb);
    bz  = b2[u] + b2[96 + u];
    br  = b2[32 + u] + b2[96 + 32 + u];
    bxh = b2[64 + u];
    bhh = b2[96 + 64 + u];
    P0b = &h1_lds[0][col * SH1 + kb]; DP = BT * SH1;
    O0b = &h2_lds[0][col * SH1 + kb]; DO = BT * SH1;
    Wwr0 = &h2_lds[0][rowq * SH1 + (w - 8) * 16 + col];
    WD = BT * SH1; wstride = SH1;
  } else {
    lay = 3; doLo = doHi = true;
    const int u = (w - 10) * 16 + col;
    WzP = bfragW(k3, 32, 96, u, kb);
    WrP = bfragW(k3, 32, 96, 32 + u, kb);
    WgP = bfragW(k3, 32, 96, 64 + u, kb);
    WzO = bfragW(rk3, 32, 96, u, kb);
    WrO = bfragW(rk3, 32, 96, 32 + u, kb);
    WgO = bfragW(rk3, 32, 96, 64 + u, kb);
    bz  = b3[u] + b3[96 + u];
    br  = b3[32 + u] + b3[96 + 32 + u];
    bxh = b3[64 + u];
    bhh = b3[96 + 64 + u];
    P0b = &h2_lds[0][col * SH1 + kb]; DP = BT * SH1;
    O0b = &h3_lds[0][col * SH1 + kb]; DO = BT * SH1;
    Wwr0 = &h3_lds[0][rowq * SH1 + (w - 10) * 16 + col];
    WD = BT * SH1; wstride = SH1;
  }

  const __bf16* xb = &x_ch[col * 40 + kb];  // L0 x A-frag base (per t-plane)

  // ------------- zero-init h state (both parities) -------------
  {
    __bf16* p0 = (__bf16*)h0_lds;
    for (int i = tid; i < 2 * BT * SH0; i += NTHR) p0[i] = (__bf16)0.f;
    __bf16* p1 = (__bf16*)h1_lds;
    __bf16* p2 = (__bf16*)h2_lds;
    __bf16* p3 = (__bf16*)h3_lds;
    for (int i = tid; i < 2 * BT * SH1; i += NTHR) {
      p1[i] = (__bf16)0.f; p2[i] = (__bf16)0.f; p3[i] = (__bf16)0.f;
    }
  }
  float hreg[4] = {0.f, 0.f, 0.f, 0.f};
  bf16x8 P0 = zf, X1 = zf;
  __syncthreads();

  for (int s = 0; s < TT + 6; ++s) {
    // ---- bulk x staging every CH steps ----
    if ((s & (CH - 1)) == 0 && s < TT) {
      for (int idx = tid; idx < BT * CH; idx += NTHR) {
        const int row = idx >> 6;          // CH = 64
        const int tg  = idx & (CH - 1);
        const float* p = binp + ((long)row * TT + s + tg) * FF;
        float4 v0 = *(const float4*)(p);
        float4 v1 = *(const float4*)(p + 4);
        float4 v2 = *(const float4*)(p + 8);
        float4 v3 = *(const float4*)(p + 12);
        float4 v4 = *(const float4*)(p + 16);
        float4 e  = *(const float4*)(Wemb + 4 * (int)v0.y);
        __bf16* d = &x_ch[tg * XSTR + row * 40];
        bf16x8 q0 = {(__bf16)v0.x, (__bf16)v0.z, (__bf16)v0.w, (__bf16)v1.x,
                     (__bf16)v1.y, (__bf16)v1.z, (__bf16)v1.w, (__bf16)v2.x};
        bf16x8 q1 = {(__bf16)v2.y, (__bf16)v2.z, (__bf16)v2.w, (__bf16)v3.x,
                     (__bf16)v3.y, (__bf16)v3.z, (__bf16)v3.w, (__bf16)v4.x};
        bf16x8 q2 = {(__bf16)v4.y, (__bf16)v4.z, (__bf16)v4.w, (__bf16)e.x,
                     (__bf16)e.y,  (__bf16)e.z,  (__bf16)e.w,  (__bf16)0.f};
        *(bf16x8*)(d)      = q0;
        *(bf16x8*)(d + 8)  = q1;
        *(bf16x8*)(d + 16) = q2;
        *(bf16x8*)(d + 24) = zf;
      }
      __syncthreads();
      // deferred/initial x load for L0 (plane 0 of the fresh chunk)
      if (lay == 0) P0 = *(const bf16x8*)(xb);
    }

    const int pb = (s + 1) & 1;  // everything written LAST step lives here
    const int qb = s & 1;        // this step's writes
    const int t  = s - 2 * lay;
    const bool active = (t >= 0) && (t < TT);

    f32x4 az, ar, axh, ahh;
    bf16x8 O0;
    if (active) {
      // own recurrent frag: written last step -> post-barrier read, issued first
      O0 = *(const bf16x8*)(O0b + pb * DO);
      if (hasX1own) X1 = *(const bf16x8*)(X1b + pb * DX);
      az  = f32x4{bz, bz, bz, bz};
      ar  = f32x4{br, br, br, br};
      axh = f32x4{bxh, bxh, bxh, bxh};
      ahh = f32x4{bhh, bhh, bhh, bhh};
      // MFMAs on prefetched regs first (cover the O0/X1 ds_read latency)
      az  = mfma16(P0, WzP, az);
      ar  = mfma16(P0, WrP, ar);
      axh = mfma16(P0, WgP, axh);
      if (hasX1pre) {               // L1: X1 = prefetched h0 kt1 (input side)
        az  = mfma16(X1, WzX, az);
        ar  = mfma16(X1, WrX, ar);
        axh = mfma16(X1, WgX, axh);
      }
      az  = mfma16(O0, WzO, az);
      ar  = mfma16(O0, WrO, ar);
      ahh = mfma16(O0, WgO, ahh);
      if (hasX1own) {               // L0: X1 = own h0 kt1 (recurrent side)
        az  = mfma16(X1, WzX, az);
        ar  = mfma16(X1, WrX, ar);
        ahh = mfma16(X1, WgX, ahh);
      }
    }

    // ---- prefetch cross inputs for step s+1 (values written last step) ----
    const int tn = t + 1;
    if (tn >= 0 && tn < TT) {
      if (lay == 0) {
        const int pl = (s + 1) & (CH - 1);
        if (pl != 0) P0 = *(const bf16x8*)(xb + pl * XSTR);
        // pl==0: next chunk staged at step s+1; deferred load there
      } else {
        P0 = *(const bf16x8*)(P0b + pb * DP);
        if (hasX1pre) X1 = *(const bf16x8*)(X1b + pb * DX);
      }
    }

    if (active) {
      __bf16* wr = Wwr0 + qb * WD;
      // 5-trans gates: merged rcp for the z/r sigmoid pair.
      // clamp +-44 keeps (1+Ez)(1+Er) finite; tanh is inf-safe via HW rcp.
#define GATE(r) { \
        float yz = fminf(fmaxf(az[r], -44.f), 44.f) * -LOG2E; \
        float yr = fminf(fmaxf(ar[r], -44.f), 44.f) * -LOG2E; \
        float Ez = __builtin_amdgcn_exp2f(yz); \
        float Er = __builtin_amdgcn_exp2f(yr); \
        float dz = 1.f + Ez, dr = 1.f + Er; \
        float inv = __builtin_amdgcn_rcpf(dz * dr); \
        float z  = inv * dr; \
        float rg = inv * dz; \
        float uu = fmaf(rg, ahh[r], axh[r]); \
        float Eg = __builtin_amdgcn_exp2f(uu * (-2.f * LOG2E)); \
        float hc = fmaf(2.f, __builtin_amdgcn_rcpf(1.f + Eg), -1.f); \
        float hn = fmaf(z, hreg[r] - hc, hc); \
        hreg[r] = hn; \
        wr[(r) * wstride] = (__bf16)hn; }

      if (doLo) { GATE(0); GATE(1); }
      if (doHi) { GATE(2); GATE(3); }
#undef GATE
    }

    __syncthreads();   // single per-step barrier
  }

  // ------------- epilogue: logits + softmax -------------
  if (w >= 10) {
#pragma unroll
    for (int r = 0; r < 4; ++r)
      h3f[(rowq + r) * 32 + (w - 10) * 16 + col] = hreg[r];
  }
  __syncthreads();

  if (tid < BT) {
    float l0 = bd[0], l1 = bd[1];
#pragma unroll
    for (int u = 0; u < 32; ++u) {
      float h = h3f[tid * 32 + u];
      l0 = fmaf(h, Wd[2 * u], l0);
      l1 = fmaf(h, Wd[2 * u + 1], l1);
    }
    float m = fmaxf(l0, l1);
    float e0 = __builtin_amdgcn_exp2f((l0 - m) * LOG2E);
    float e1 = __builtin_amdgcn_exp2f((l1 - m) * LOG2E);
    float inv = 1.f / (e0 + e1);
    out[(bbase + tid) * 2 + 0] = e0 * inv;
    out[(bbase + tid) * 2 + 1] = e1 * inv;
  }
}

extern "C" void kernel_launch(void* const* d_in, const int* in_sizes, int n_in,
                              void* d_out, int out_size, void* d_ws, size_t ws_size,
                              hipStream_t stream) {
  const float* inp  = (const float*)d_in[0];
  const float* Wemb = (const float*)d_in[1];
  const float* k0   = (const float*)d_in[2];
  const float* rk0  = (const float*)d_in[3];
  const float* b0   = (const float*)d_in[4];
  const float* k1   = (const float*)d_in[5];
  const float* rk1  = (const float*)d_in[6];
  const float* b1   = (const float*)d_in[7];
  const float* k2   = (const float*)d_in[8];
  const float* rk2  = (const float*)d_in[9];
  const float* b2   = (const float*)d_in[10];
  const float* k3   = (const float*)d_in[11];
  const float* rk3  = (const float*)d_in[12];
  const float* b3   = (const float*)d_in[13];
  const float* Wd   = (const float*)d_in[14];
  const float* bd   = (const float*)d_in[15];
  float* out = (float*)d_out;

  const int Btot = in_sizes[0] / (TT * FF);   // 4096
  dim3 grid(Btot / BT);                       // 256 blocks
  gru4<<<grid, NTHR, 0, stream>>>(inp, Wemb, k0, rk0, b0, k1, rk1, b1,
                                  k2, rk2, b2, k3, rk3, b3, Wd, bd, out);
}